// Round 3
// baseline (929.688 us; speedup 1.0000x reference)
//
#include <hip/hip_runtime.h>
#include <stdint.h>

#define L 2048
#define DMODEL 2048
#define NH 16

typedef __bf16 bf16x8 __attribute__((ext_vector_type(8)));
typedef float f32x4 __attribute__((ext_vector_type(4)));
typedef short s16x4 __attribute__((ext_vector_type(4)));

__device__ __forceinline__ unsigned short f2bf(float f) {
    union { float f; unsigned int i; } w; w.f = f;
    unsigned int u = w.i;
    unsigned int r = u + 0x7fffu + ((u >> 16) & 1u);
    return (unsigned short)(r >> 16);
}

// ---------------------------------------------------------------------------
// Tiled bf16-MFMA GEMM, C = alpha * A (MxK) * B'(NxK)^T.  B' is B transposed
// (row n of B' holds column n of B, contiguous in K), always bf16.
// AF32=1: A is fp32 in memory, converted to bf16 (RNE) during LDS staging.
// CMODE 0: C bf16 row-major [m][n]   (ldc = row stride)
// CMODE 1: C bf16 transposed [n][m]  (ldc = row stride of transposed mat)
// CMODE 2: C fp32 row-major [m][n]
// Grid (N/128, M/128, batch), block 256 (4 waves).  lda/ldb/ldc/sA/sB/sC in
// ELEMENTS of the respective dtype.
// ---------------------------------------------------------------------------
template<int CMODE, int AF32>
__global__ __launch_bounds__(256, 2)
void gemm_bt(const void* __restrict__ Av,
             const unsigned short* __restrict__ B,
             void* __restrict__ C,
             int M, int N, int K, int lda, int ldb, int ldc,
             long long sA, long long sB, long long sC, float alpha)
{
    __shared__ unsigned short As[128 * 32];
    __shared__ unsigned short Bs[128 * 32];

    const int tid  = threadIdx.x;
    const int wave = tid >> 6;
    const int lane = tid & 63;
    const int quad = lane >> 4;
    const int l16  = lane & 15;

    const int tileN = blockIdx.x * 128;
    const int tileM = blockIdx.y * 128;

    const unsigned short* A16 = (const unsigned short*)Av + (AF32 ? 0 : (long long)blockIdx.z * sA);
    const float*          A32 = (const float*)Av          + (AF32 ? (long long)blockIdx.z * sA : 0);
    B += (long long)blockIdx.z * sB;

    const int wm = (wave >> 1) * 64;
    const int wn = (wave & 1) * 64;

    // 512 16B chunks cover a 128x32 bf16 tile; thread stages chunks tid, tid+256.
    // chunk ch -> row = ch>>2, k-offset = (ch&3)*8; LDS elem offset = ch*8.
    const int ch0 = tid, ch1 = tid + 256;
    const int r0a = ch0 >> 2, kc0 = (ch0 & 3) * 8;
    const int r1a = ch1 >> 2, kc1 = (ch1 & 3) * 8;

    f32x4 acc[4][4] = {};

    for (int k0 = 0; k0 < K; k0 += 32) {
        int4 a0, a1;
        if (AF32) {
            const float* p0 = A32 + (long long)(tileM + r0a) * lda + (k0 + kc0);
            const float* p1 = A32 + (long long)(tileM + r1a) * lda + (k0 + kc1);
            const float4 f00 = *(const float4*)p0;
            const float4 f01 = *(const float4*)(p0 + 4);
            const float4 f10 = *(const float4*)p1;
            const float4 f11 = *(const float4*)(p1 + 4);
            union { int4 v; unsigned short u[8]; } t0, t1;
            t0.u[0] = f2bf(f00.x); t0.u[1] = f2bf(f00.y); t0.u[2] = f2bf(f00.z); t0.u[3] = f2bf(f00.w);
            t0.u[4] = f2bf(f01.x); t0.u[5] = f2bf(f01.y); t0.u[6] = f2bf(f01.z); t0.u[7] = f2bf(f01.w);
            t1.u[0] = f2bf(f10.x); t1.u[1] = f2bf(f10.y); t1.u[2] = f2bf(f10.z); t1.u[3] = f2bf(f10.w);
            t1.u[4] = f2bf(f11.x); t1.u[5] = f2bf(f11.y); t1.u[6] = f2bf(f11.z); t1.u[7] = f2bf(f11.w);
            a0 = t0.v; a1 = t1.v;
        } else {
            a0 = *(const int4*)(A16 + (long long)(tileM + r0a) * lda + (k0 + kc0));
            a1 = *(const int4*)(A16 + (long long)(tileM + r1a) * lda + (k0 + kc1));
        }
        const int4 b0 = *(const int4*)(B + (long long)(tileN + r0a) * ldb + (k0 + kc0));
        const int4 b1 = *(const int4*)(B + (long long)(tileN + r1a) * ldb + (k0 + kc1));

        __syncthreads();             // previous iteration's LDS reads complete
        *(int4*)(As + ch0 * 8) = a0;
        *(int4*)(As + ch1 * 8) = a1;
        *(int4*)(Bs + ch0 * 8) = b0;
        *(int4*)(Bs + ch1 * 8) = b1;
        __syncthreads();             // staging visible

        bf16x8 af[4], bfr[4];
        #pragma unroll
        for (int i = 0; i < 4; ++i)
            af[i] = *(const bf16x8*)(As + (wm + i * 16 + l16) * 32 + quad * 8);
        #pragma unroll
        for (int i = 0; i < 4; ++i)
            bfr[i] = *(const bf16x8*)(Bs + (wn + i * 16 + l16) * 32 + quad * 8);
        #pragma unroll
        for (int i = 0; i < 4; ++i)
            #pragma unroll
            for (int j = 0; j < 4; ++j)
                acc[i][j] = __builtin_amdgcn_mfma_f32_16x16x32_bf16(af[i], bfr[j], acc[i][j], 0, 0, 0);
    }

    // Epilogue.  D layout: col = lane&15, row = quad*4 + reg   [m89-verified]
    const long long cb = (long long)blockIdx.z * sC;
    #pragma unroll
    for (int i = 0; i < 4; ++i) {
        const int r0 = tileM + wm + i * 16 + quad * 4;
        #pragma unroll
        for (int j = 0; j < 4; ++j) {
            const int c = tileN + wn + j * 16 + l16;
            f32x4 d = acc[i][j];
            if (CMODE == 0) {
                unsigned short* Cp = (unsigned short*)C + cb;
                #pragma unroll
                for (int r = 0; r < 4; ++r)
                    Cp[(long long)(r0 + r) * ldc + c] = f2bf(d[r] * alpha);
            } else if (CMODE == 1) {
                unsigned short* Cp = (unsigned short*)C + cb + (long long)c * ldc + r0;
                s16x4 pk;
                #pragma unroll
                for (int r = 0; r < 4; ++r) pk[r] = (short)f2bf(d[r] * alpha);
                *(s16x4*)Cp = pk;
            } else {
                float* Cp = (float*)C + cb;
                #pragma unroll
                for (int r = 0; r < 4; ++r)
                    Cp[(long long)(r0 + r) * ldc + c] = d[r] * alpha;
            }
        }
    }
}

// ---------------------------------------------------------------------------
// 32x32 tile transpose, fp32 in -> bf16 out. Block (32,8).
// Grid (cols/32, rows/32, batch).  out[c][r] = bf16(in[r][c])
// ---------------------------------------------------------------------------
__global__ __launch_bounds__(256)
void transpose_f2b(const float* __restrict__ in, unsigned short* __restrict__ out,
                   int rows, int cols)
{
    __shared__ float t[32][33];
    const long long base = (long long)blockIdx.z * rows * cols;
    const int c0 = blockIdx.x * 32, r0 = blockIdx.y * 32;
    const int tx = threadIdx.x, ty0 = threadIdx.y;
    #pragma unroll
    for (int jj = 0; jj < 4; ++jj) {
        const int j = ty0 + jj * 8;
        t[j][tx] = in[base + (long long)(r0 + j) * cols + (c0 + tx)];
    }
    __syncthreads();
    #pragma unroll
    for (int jj = 0; jj < 4; ++jj) {
        const int j = ty0 + jj * 8;
        out[base + (long long)(c0 + j) * rows + (r0 + tx)] = f2bf(t[tx][j]);
    }
}

// ---------------------------------------------------------------------------
// Softmax over the QUERY axis (rows) of each head's row-major (Lq x Lk) fp32
// logits, in place. Block (256 cols, 4 row-slices). Grid (Lk/256, NH).
// ---------------------------------------------------------------------------
__global__ __launch_bounds__(1024)
void col_softmax(float* __restrict__ S)
{
    __shared__ float shm[4][256], shl[4][256];
    const int tx = threadIdx.x, ty = threadIdx.y;
    const int c = blockIdx.x * 256 + tx;
    float* P = S + (long long)blockIdx.y * L * L + c;
    const int r0 = ty * (L / 4), r1 = r0 + (L / 4);

    float mmax = -1e30f, ssum = 0.f;
    for (int r = r0; r < r1; ++r) {
        float s = P[(long long)r * L];
        float mn = fmaxf(mmax, s);
        ssum = ssum * __expf(mmax - mn) + __expf(s - mn);
        mmax = mn;
    }
    shm[ty][tx] = mmax; shl[ty][tx] = ssum;
    __syncthreads();
    float M = -1e30f;
    #pragma unroll
    for (int t = 0; t < 4; ++t) M = fmaxf(M, shm[t][tx]);
    float Ls = 0.f;
    #pragma unroll
    for (int t = 0; t < 4; ++t) Ls += shl[t][tx] * __expf(shm[t][tx] - M);
    const float inv = 1.0f / Ls;
    for (int r = r0; r < r1; ++r) {
        float* p = P + (long long)r * L;
        *p = __expf(*p - M) * inv;
    }
}

// ---------------------------------------------------------------------------
// Residual + bias + LayerNorm (all fp32), one block (256 thr) per row of 2048.
// ---------------------------------------------------------------------------
__global__ __launch_bounds__(256)
void ln_resid(const float* __restrict__ ypre, const float* __restrict__ resid,
              const float* __restrict__ pb, const float* __restrict__ g,
              const float* __restrict__ bta, float* __restrict__ y)
{
    __shared__ float as_[4], as2_[4];
    const int l = blockIdx.x;
    const int tid = threadIdx.x;
    float v[8]; float s = 0.f, s2 = 0.f;
    #pragma unroll
    for (int i = 0; i < 8; ++i) {
        const int d = tid + i * 256;
        float t = ypre[(long long)l * DMODEL + d] + pb[d] + resid[(long long)l * DMODEL + d];
        v[i] = t; s += t; s2 += t * t;
    }
    #pragma unroll
    for (int off = 32; off > 0; off >>= 1) {
        s  += __shfl_down(s, off, 64);
        s2 += __shfl_down(s2, off, 64);
    }
    const int wave = tid >> 6, lane = tid & 63;
    if (lane == 0) { as_[wave] = s; as2_[wave] = s2; }
    __syncthreads();
    const float S  = as_[0] + as_[1] + as_[2] + as_[3];
    const float S2 = as2_[0] + as2_[1] + as2_[2] + as2_[3];
    const float mu  = S * (1.0f / DMODEL);
    const float var = S2 * (1.0f / DMODEL) - mu * mu;
    const float rs  = rsqrtf(var + 1e-5f);
    #pragma unroll
    for (int i = 0; i < 8; ++i) {
        const int d = tid + i * 256;
        y[(long long)l * DMODEL + d] = (v[i] - mu) * rs * g[d] + bta[d];
    }
}

// ---------------------------------------------------------------------------
extern "C" void kernel_launch(void* const* d_in, const int* in_sizes, int n_in,
                              void* d_out, int out_size, void* d_ws, size_t ws_size,
                              hipStream_t stream)
{
    const float* q  = (const float*)d_in[0];
    const float* k  = (const float*)d_in[1];
    const float* v  = (const float*)d_in[2];
    const float* Wq = (const float*)d_in[3];
    const float* Wk = (const float*)d_in[4];
    const float* Wv = (const float*)d_in[5];
    const float* Pw = (const float*)d_in[6];
    const float* Pb = (const float*)d_in[7];
    const float* Lg = (const float*)d_in[8];
    const float* Lb = (const float*)d_in[9];

    float* y    = (float*)d_out;
    float* attn = y + (size_t)L * DMODEL;               // output 1 (fp32), 67.1M elems

    // ws layout (bf16 elems unless noted), 40 MB total:
    //   T0  [ 0, 8MB)  transposed weights (reused sequentially)
    //   qh  [ 8,16MB)  kh [16,24MB)  vhT [24,32MB)  O [32,40MB)
    //   ypre fp32 16MB overlays qh+kh (dead after the scores GEMM)
    const size_t SEG = (size_t)4194304;
    unsigned short* T0  = (unsigned short*)d_ws;
    unsigned short* qh  = T0 + SEG;
    unsigned short* kh  = qh + SEG;
    unsigned short* vhT = kh + SEG;
    unsigned short* O   = vhT + SEG;
    float* ypre = (float*)qh;

    const float inv_temper = 0.022097086912079608f;     // 1/sqrt(2048)
    dim3 tb(32, 8);

    // qh[h] = (q @ Wq[h]) / temper      (A fp32, M=2048,N=128,K=2048)
    transpose_f2b<<<dim3(4, 64, 16), tb, 0, stream>>>(Wq, T0, 2048, 128);
    gemm_bt<0, 1><<<dim3(1, 16, 16), 256, 0, stream>>>(q, T0, qh, 2048, 128, 2048,
        2048, 2048, 128, 0LL, 262144LL, 262144LL, inv_temper);
    // kh[h] = k @ Wk[h]
    transpose_f2b<<<dim3(4, 64, 16), tb, 0, stream>>>(Wk, T0, 2048, 128);
    gemm_bt<0, 1><<<dim3(1, 16, 16), 256, 0, stream>>>(k, T0, kh, 2048, 128, 2048,
        2048, 2048, 128, 0LL, 262144LL, 262144LL, 1.0f);
    // vhT[h] = (v @ Wv[h])^T  -> [vd][m]
    transpose_f2b<<<dim3(4, 64, 16), tb, 0, stream>>>(Wv, T0, 2048, 128);
    gemm_bt<1, 1><<<dim3(1, 16, 16), 256, 0, stream>>>(v, T0, vhT, 2048, 128, 2048,
        2048, 2048, 2048, 0LL, 262144LL, 262144LL, 1.0f);

    // logits[h] = qh[h] @ kh[h]^T  -> fp32 attn region (M=N=2048, K=128)
    gemm_bt<2, 0><<<dim3(16, 16, 16), 256, 0, stream>>>(qh, kh, attn, 2048, 2048, 128,
        128, 128, 2048, 262144LL, 262144LL, 4194304LL, 1.0f);

    // softmax over the query axis, in place (fp32)
    col_softmax<<<dim3(8, NH), dim3(256, 4), 0, stream>>>(attn);

    // O[l, h*128+vd] = attn[h] @ vh[h]   (A fp32)
    gemm_bt<0, 1><<<dim3(1, 16, 16), 256, 0, stream>>>(attn, vhT, O, 2048, 128, 2048,
        2048, 2048, 2048, 4194304LL, 262144LL, 128LL, 1.0f);

    // ypre = O @ proj_w   (fp32 out, M=N=K=2048)
    transpose_f2b<<<dim3(64, 64, 1), tb, 0, stream>>>(Pw, T0, 2048, 2048);
    gemm_bt<2, 0><<<dim3(16, 16, 1), 256, 0, stream>>>(O, T0, (void*)ypre, 2048, 2048, 2048,
        2048, 2048, 2048, 0LL, 0LL, 0LL, 1.0f);

    // y = LayerNorm(ypre + proj_b + residual) * g + b
    ln_resid<<<dim3(2048), 256, 0, stream>>>(ypre, q, Pb, Lg, Lb, y);
}